// Round 7
// baseline (353.582 us; speedup 1.0000x reference)
//
#include <hip/hip_runtime.h>
#include <math.h>

// DTW loss: B=128, L1=L2=512, D=16.
// R7: ANTI-DIAGONAL DP. One block (9 waves) per batch:
//   wave 0   = consumer: per diagonal d, N[j] = c + min3(P[j], P[j-1], Q[j-1]).
//              8 cols/lane blocked; only 2 DPP wave_shr per step (lane boundary),
//              both off the dependent chain. No wave-scan.
//   waves1-8 = producers: 1 col/lane (y resident), fill LDS cost bands of
//              DEPTH=15 diagonals, double-buffered; rows clamped so every band
//              cell is written (garbage shielded by BIG arithmetic).
// One __syncthreads per band (70 total). Inactive columns carry BIG=3e38:
// BIG + cost stays exactly 3e38 in fp32; boundary rules emerge from BIG P/Q.

#define TL 512
#define TD 16
#define TNB 128
#define BIGF 3.0e38f
#define DEPTH 15
#define NBAND 69   // bands 0..68 cover diagonals 0..1034 (need 0..1022)

typedef float f32x2 __attribute__((ext_vector_type(2)));
typedef float f32x4 __attribute__((ext_vector_type(4)));

__device__ inline f32x2 pk_fma(f32x2 a, f32x2 b, f32x2 c) {
    f32x2 d;
    asm("v_pk_fma_f32 %0, %1, %2, %3" : "=v"(d) : "v"(a), "v"(b), "v"(c));
    return d;
}
__device__ inline f32x2 pk_mul(f32x2 a, f32x2 b) {
    f32x2 d;
    asm("v_pk_mul_f32 %0, %1, %2" : "=v"(d) : "v"(a), "v"(b));
    return d;
}
__device__ inline float min3f(float a, float b, float c) {
    float d;
    asm("v_min3_f32 %0, %1, %2, %3" : "=v"(d) : "v"(a), "v"(b), "v"(c));
    return d;
}
template<int CTRL, int RM, bool BC>
__device__ inline float dpp_mov(float old_, float src) {
    return __int_as_float(__builtin_amdgcn_update_dpp(
        __float_as_int(old_), __float_as_int(src), CTRL, RM, 0xf, BC));
}

// one diagonal step: PC = diag d-1, PO = diag d-2 (overwritten with diag d)
#define CSTEP(PC, PO, DD) \
    if (dc0 + (DD) < 1023) { \
        const float* crp = &band[cb][DD][8 * t]; \
        const f32x4 cA = *(const f32x4*)crp; \
        const f32x4 cB = *(const f32x4*)(crp + 4); \
        const float l1 = dpp_mov<0x138, 0xf, false>(BIGF, PC[7]); \
        const float l2 = dpp_mov<0x138, 0xf, false>(BIGF, PO[7]); \
        float n0 = min3f(PC[0], l1, l2); \
        float n1 = min3f(PC[1], PC[0], PO[0]); \
        float n2 = min3f(PC[2], PC[1], PO[1]); \
        float n3 = min3f(PC[3], PC[2], PO[2]); \
        float n4 = min3f(PC[4], PC[3], PO[3]); \
        float n5 = min3f(PC[5], PC[4], PO[4]); \
        float n6 = min3f(PC[6], PC[5], PO[5]); \
        float n7 = min3f(PC[7], PC[6], PO[6]); \
        PO[0] = cA.x + n0; PO[1] = cA.y + n1; \
        PO[2] = cA.z + n2; PO[3] = cA.w + n3; \
        PO[4] = cB.x + n4; PO[5] = cB.y + n5; \
        PO[6] = cB.z + n6; PO[7] = cB.w + n7; \
        if ((DD) == 0 && dc0 == 0) { if (t == 0) PO[0] = cA.x; } \
    }

#define CONSBAND(PX, PY) { \
    CSTEP(PX, PY, 0)  CSTEP(PY, PX, 1)  CSTEP(PX, PY, 2)  CSTEP(PY, PX, 3) \
    CSTEP(PX, PY, 4)  CSTEP(PY, PX, 5)  CSTEP(PX, PY, 6)  CSTEP(PY, PX, 7) \
    CSTEP(PX, PY, 8)  CSTEP(PY, PX, 9)  CSTEP(PX, PY, 10) CSTEP(PY, PX, 11) \
    CSTEP(PX, PY, 12) CSTEP(PY, PX, 13) CSTEP(PX, PY, 14) \
}

__global__ __launch_bounds__(576, 3) void dtw_fused_kernel(const float* __restrict__ s1,
                                                           const float* __restrict__ s2,
                                                           float* __restrict__ ws) {
    const int b   = blockIdx.x;
    const int tid = threadIdx.x;
    const int w   = tid >> 6;    // 0 = consumer, 1..8 producers
    const int t   = tid & 63;

    __shared__ float xsq[TL];                 // 2 KB
    __shared__ float band[2][DEPTH][TL];      // 60 KB

    const float* s1b = s1 + (size_t)b * TL * TD;

    // consumer state: two previous diagonals (8 cols/lane, blocked)
    float Pa[8], Pb[8];

    // producer state: 1 column/lane, y resident
    int j = 0;
    float ysq = 0.f;
    f32x2 y0v, y1v, y2v, y3v, y4v, y5v, y6v, y7v;

    if (w > 0) {
        j = (w - 1) * 64 + t;
        const f32x4* yp = (const f32x4*)(s2 + ((size_t)b * TL + j) * TD);
        f32x4 q0 = yp[0], q1 = yp[1], q2 = yp[2], q3 = yp[3];
        y0v = f32x2{q0.x, q0.y}; y1v = f32x2{q0.z, q0.w};
        y2v = f32x2{q1.x, q1.y}; y3v = f32x2{q1.z, q1.w};
        y4v = f32x2{q2.x, q2.y}; y5v = f32x2{q2.z, q2.w};
        y6v = f32x2{q3.x, q3.y}; y7v = f32x2{q3.z, q3.w};
        f32x2 a_ = pk_mul(y0v, y0v);
        a_ = pk_fma(y1v, y1v, a_); a_ = pk_fma(y2v, y2v, a_);
        a_ = pk_fma(y3v, y3v, a_); a_ = pk_fma(y4v, y4v, a_);
        a_ = pk_fma(y5v, y5v, a_); a_ = pk_fma(y6v, y6v, a_);
        a_ = pk_fma(y7v, y7v, a_);
        ysq = a_.x + a_.y;
        // xsq for row index j (waves 1..8 cover rows 0..511 exactly)
        const f32x4* xp = (const f32x4*)(s1b + j * TD);
        f32x4 p0 = xp[0], p1 = xp[1], p2 = xp[2], p3 = xp[3];
        f32x2 b0 = pk_mul(f32x2{p0.x, p0.y}, f32x2{p0.x, p0.y});
        b0 = pk_fma(f32x2{p0.z, p0.w}, f32x2{p0.z, p0.w}, b0);
        b0 = pk_fma(f32x2{p1.x, p1.y}, f32x2{p1.x, p1.y}, b0);
        b0 = pk_fma(f32x2{p1.z, p1.w}, f32x2{p1.z, p1.w}, b0);
        b0 = pk_fma(f32x2{p2.x, p2.y}, f32x2{p2.x, p2.y}, b0);
        b0 = pk_fma(f32x2{p2.z, p2.w}, f32x2{p2.z, p2.w}, b0);
        b0 = pk_fma(f32x2{p3.x, p3.y}, f32x2{p3.x, p3.y}, b0);
        b0 = pk_fma(f32x2{p3.z, p3.w}, f32x2{p3.z, p3.w}, b0);
        xsq[j] = b0.x + b0.y;
    } else {
        #pragma unroll
        for (int k = 0; k < 8; ++k) { Pa[k] = BIGF; Pb[k] = BIGF; }
    }
    __syncthreads();

    for (int iter = 0; iter <= NBAND; ++iter) {
        if (w > 0) {
            if (iter < NBAND) {
                const int pb  = iter & 1;
                const int d0j = iter * DEPTH - j;
                #pragma unroll
                for (int dd = 0; dd < DEPTH; ++dd) {
                    int i = d0j + dd;
                    i = i < 0 ? 0 : i;
                    i = i > (TL - 1) ? (TL - 1) : i;   // clamp: garbage cells are
                                                      // finite and BIG-shielded
                    const f32x4* xp = (const f32x4*)(s1b + i * TD);
                    f32x4 q0 = xp[0], q1 = xp[1], q2 = xp[2], q3 = xp[3];
                    float xs = xsq[i];
                    f32x2 acc = pk_mul(f32x2{q0.x, q0.y}, y0v);
                    acc = pk_fma(f32x2{q0.z, q0.w}, y1v, acc);
                    acc = pk_fma(f32x2{q1.x, q1.y}, y2v, acc);
                    acc = pk_fma(f32x2{q1.z, q1.w}, y3v, acc);
                    acc = pk_fma(f32x2{q2.x, q2.y}, y4v, acc);
                    acc = pk_fma(f32x2{q2.z, q2.w}, y5v, acc);
                    acc = pk_fma(f32x2{q3.x, q3.y}, y6v, acc);
                    acc = pk_fma(f32x2{q3.z, q3.w}, y7v, acc);
                    float dot = acc.x + acc.y;
                    band[pb][dd][j] = fmaf(-2.f, dot, xs + ysq);
                }
            }
        } else {
            if (iter >= 1) {
                const int cb  = (iter - 1) & 1;
                const int dc0 = (iter - 1) * DEPTH;
                if (iter & 1) CONSBAND(Pa, Pb) else CONSBAND(Pb, Pa)
            }
        }
        __syncthreads();
    }

    // d=1022 lands in Pb (band 68 is A-form; its 3rd step writes Pb)
    if (w == 0 && t == 63) ws[b] = sqrtf(Pb[7]);
}

__global__ void dtw_reduce_kernel(const float* __restrict__ ws, float* __restrict__ out) {
    const int t = threadIdx.x;          // 64 threads
    float v = ws[t] + ws[t + 64];
    #pragma unroll
    for (int d2 = 32; d2 > 0; d2 >>= 1) v += __shfl_down(v, d2);
    if (t == 0) out[0] = v * (1.0f / TNB);
}

extern "C" void kernel_launch(void* const* d_in, const int* in_sizes, int n_in,
                              void* d_out, int out_size, void* d_ws, size_t ws_size,
                              hipStream_t stream) {
    const float* s1 = (const float*)d_in[0];
    const float* s2 = (const float*)d_in[1];
    float* ws  = (float*)d_ws;
    float* out = (float*)d_out;

    dtw_fused_kernel<<<TNB, 576, 0, stream>>>(s1, s2, ws);
    dtw_reduce_kernel<<<1, 64, 0, stream>>>(ws, out);
}

// Round 8
// 146.294 us; speedup vs baseline: 2.4169x; 2.4169x over previous
//
#include <hip/hip_runtime.h>
#include <math.h>

// DTW loss: B=128, L1=L2=512, D=16.
// R8: FULLY SYSTOLIC single wave per batch (skewed schedule).
// Lane j owns cols 8j..8j+7 (y resident, 128 VGPRs). At step s lane j
// processes row i = s-j: 8 serial DP cells (min3+add). Neighbor values via
// 2 wave_shr:1 DPPs. x rows read from a stride-20 LDS copy of s1 (staged
// once; bank-balanced, 16B-aligned), double-buffered one step ahead.
// Inactive lanes frozen via cndmask; BIG arithmetic shields boundaries.
// No barriers, no producer waves, no wave-scan.

#define TL 512
#define TD 16
#define TNB 128
#define BIGF 3.0e38f
#define XSTRIDE 20   // floats per padded LDS row (80 B: aligned + bank-balanced)

typedef float f32x2 __attribute__((ext_vector_type(2)));
typedef float f32x4 __attribute__((ext_vector_type(4)));

__device__ inline f32x2 pk_fma(f32x2 a, f32x2 b, f32x2 c) {
    f32x2 d;
    asm("v_pk_fma_f32 %0, %1, %2, %3" : "=v"(d) : "v"(a), "v"(b), "v"(c));
    return d;
}
__device__ inline f32x2 pk_mul(f32x2 a, f32x2 b) {
    f32x2 d;
    asm("v_pk_mul_f32 %0, %1, %2" : "=v"(d) : "v"(a), "v"(b));
    return d;
}
__device__ inline float min3f(float a, float b, float c) {
    float d;
    asm("v_min3_f32 %0, %1, %2, %3" : "=v"(d) : "v"(a), "v"(b), "v"(c));
    return d;
}
template<int CTRL, int RM, bool BC>
__device__ inline float dpp_mov(float old_, float src) {
    return __int_as_float(__builtin_amdgcn_update_dpp(
        __float_as_int(old_), __float_as_int(src), CTRL, RM, 0xf, BC));
}

struct XRow { f32x4 q[4]; float sq; };

__device__ inline void issue_load(const float* __restrict__ xlds,
                                  const float* __restrict__ xsql,
                                  int s, int t, XRow& dst) {
    int i = s - t;
    i = i < 0 ? 0 : i;
    i = i > (TL - 1) ? (TL - 1) : i;      // clamp: garbage shielded by BIG
    const f32x4* p = (const f32x4*)(xlds + i * XSTRIDE);
    dst.q[0] = p[0]; dst.q[1] = p[1]; dst.q[2] = p[2]; dst.q[3] = p[3];
    dst.sq = xsql[i];
}

__device__ inline void step(const XRow& x, const f32x2 (&y2)[8][8],
                            const float (&ysq)[8], float (&pv)[8],
                            float& o7, int s, int t) {
    f32x2 xp[8];
    xp[0] = f32x2{x.q[0].x, x.q[0].y}; xp[1] = f32x2{x.q[0].z, x.q[0].w};
    xp[2] = f32x2{x.q[1].x, x.q[1].y}; xp[3] = f32x2{x.q[1].z, x.q[1].w};
    xp[4] = f32x2{x.q[2].x, x.q[2].y}; xp[5] = f32x2{x.q[2].z, x.q[2].w};
    xp[6] = f32x2{x.q[3].x, x.q[3].y}; xp[7] = f32x2{x.q[3].z, x.q[3].w};

    float cc[8];
    #pragma unroll
    for (int k = 0; k < 8; ++k) {
        f32x2 acc = pk_mul(xp[0], y2[k][0]);
        #pragma unroll
        for (int p = 1; p < 8; ++p) acc = pk_fma(xp[p], y2[k][p], acc);
        cc[k] = fmaf(-2.f, acc.x + acc.y, x.sq + ysq[k]);
    }

    // neighbor values (lane j-1): left = DTW[i][8j-1], diag = DTW[i-1][8j-1]
    const float left  = dpp_mov<0x138, 0xf, false>(BIGF, pv[7]);
    const float sdiag = (s == 0) ? 0.0f : BIGF;       // seeds DTW[-1][-1]=0
    const float diag  = dpp_mov<0x138, 0xf, false>(sdiag, o7);
    o7 = pv[7];                                       // pv[7] before update

    float v[8];
    float n0 = min3f(pv[0], left, diag);
    v[0] = cc[0] + n0;
    #pragma unroll
    for (int k = 1; k < 8; ++k) {
        float nk = min3f(pv[k], v[k - 1], pv[k - 1]);
        v[k] = cc[k] + nk;
    }

    const bool act = (unsigned)(s - t) < (unsigned)TL;
    #pragma unroll
    for (int k = 0; k < 8; ++k) pv[k] = act ? v[k] : pv[k];
}

__global__ __launch_bounds__(64, 1) void dtw_systolic_kernel(const float* __restrict__ s1,
                                                             const float* __restrict__ s2,
                                                             float* __restrict__ ws) {
    const int b = blockIdx.x;
    const int t = threadIdx.x;   // lane 0..63

    __shared__ float xlds[TL * XSTRIDE];   // 40 KB padded s1 copy
    __shared__ float xsql[TL];             // 2 KB row sumsq

    const float* s1b = s1 + (size_t)b * TL * TD;

    // stage s1 -> LDS (stride 20) + row sumsq; 8 rows per lane
    #pragma unroll
    for (int k8 = 0; k8 < 8; ++k8) {
        const int r = t + 64 * k8;
        const f32x4* src = (const f32x4*)(s1b + r * TD);
        f32x4 q0 = src[0], q1 = src[1], q2 = src[2], q3 = src[3];
        f32x4* dst = (f32x4*)(xlds + r * XSTRIDE);
        dst[0] = q0; dst[1] = q1; dst[2] = q2; dst[3] = q3;
        f32x2 a_ = pk_mul(f32x2{q0.x, q0.y}, f32x2{q0.x, q0.y});
        a_ = pk_fma(f32x2{q0.z, q0.w}, f32x2{q0.z, q0.w}, a_);
        a_ = pk_fma(f32x2{q1.x, q1.y}, f32x2{q1.x, q1.y}, a_);
        a_ = pk_fma(f32x2{q1.z, q1.w}, f32x2{q1.z, q1.w}, a_);
        a_ = pk_fma(f32x2{q2.x, q2.y}, f32x2{q2.x, q2.y}, a_);
        a_ = pk_fma(f32x2{q2.z, q2.w}, f32x2{q2.z, q2.w}, a_);
        a_ = pk_fma(f32x2{q3.x, q3.y}, f32x2{q3.x, q3.y}, a_);
        a_ = pk_fma(f32x2{q3.z, q3.w}, f32x2{q3.z, q3.w}, a_);
        xsql[r] = a_.x + a_.y;
    }

    // y tile: 8 cols/lane resident + ysq
    const float* s2b = s2 + ((size_t)b * TL + 8 * (size_t)t) * TD;
    f32x2 y2[8][8];
    float ysq[8];
    #pragma unroll
    for (int k = 0; k < 8; ++k) {
        #pragma unroll
        for (int p = 0; p < 8; ++p)
            y2[k][p] = *reinterpret_cast<const f32x2*>(s2b + k * TD + 2 * p);
        f32x2 acc = pk_mul(y2[k][0], y2[k][0]);
        #pragma unroll
        for (int p = 1; p < 8; ++p) acc = pk_fma(y2[k][p], y2[k][p], acc);
        ysq[k] = acc.x + acc.y;
    }

    __syncthreads();   // single wave: just drains LDS writes

    float pv[8];
    #pragma unroll
    for (int k = 0; k < 8; ++k) pv[k] = BIGF;
    float o7 = BIGF;

    XRow xa, xb;
    issue_load(xlds, xsql, 0, t, xa);

    // 576 steps (s = 0..575); last needed is s=574 (lane 63, row 511);
    // step 575 is frozen for all lanes (harmless).
    for (int s = 0; s < 576; s += 2) {
        issue_load(xlds, xsql, s + 1, t, xb);
        step(xa, y2, ysq, pv, o7, s, t);
        issue_load(xlds, xsql, s + 2, t, xa);
        step(xb, y2, ysq, pv, o7, s + 1, t);
    }

    if (t == 63) ws[b] = sqrtf(pv[7]);
}

__global__ void dtw_reduce_kernel(const float* __restrict__ ws, float* __restrict__ out) {
    const int t = threadIdx.x;          // 64 threads
    float v = ws[t] + ws[t + 64];
    #pragma unroll
    for (int d2 = 32; d2 > 0; d2 >>= 1) v += __shfl_down(v, d2);
    if (t == 0) out[0] = v * (1.0f / TNB);
}

extern "C" void kernel_launch(void* const* d_in, const int* in_sizes, int n_in,
                              void* d_out, int out_size, void* d_ws, size_t ws_size,
                              hipStream_t stream) {
    const float* s1 = (const float*)d_in[0];
    const float* s2 = (const float*)d_in[1];
    float* ws  = (float*)d_ws;
    float* out = (float*)d_out;

    dtw_systolic_kernel<<<TNB, 64, 0, stream>>>(s1, s2, ws);
    dtw_reduce_kernel<<<1, 64, 0, stream>>>(ws, out);
}